// Round 7
// baseline (254.144 us; speedup 1.0000x reference)
//
#include <hip/hip_runtime.h>

#define NNODES 50000
#define NEDGES 800000
#define HIDDIM 256
#define NB_SCAN 196   // ceil(NNODES/256)

constexpr float kAlpha = 0.1f;
constexpr float kBnEps = 1e-5f;
constexpr float kBeta  = 0.40546510810816438198f;   // log(1.5)

typedef __attribute__((ext_vector_type(8))) short  bf16x8;   // 8 bf16 in 4 VGPRs
typedef __attribute__((ext_vector_type(4))) float  f32x4;

static __device__ __forceinline__ unsigned short f2bf(float f) {
  unsigned u = __float_as_uint(f);
  u = (u + 0x7FFFu + ((u >> 16) & 1u)) >> 16;      // RTNE
  return (unsigned short)u;
}
static __device__ __forceinline__ float bf2f(unsigned short h) {
  return __uint_as_float(((unsigned)h) << 16);
}

// ---------------------------------------------------------------------------
// prep: both weight transposes (fp32 [k][n] -> bf16 [n][k]) + zero BN stats
// ---------------------------------------------------------------------------
__global__ __launch_bounds__(256) void prep_k(const float* __restrict__ W_pre,
                                              const float* __restrict__ W_op,
                                              unsigned short* __restrict__ wpre_t,
                                              unsigned short* __restrict__ wop_t,
                                              float* __restrict__ colsum,
                                              float* __restrict__ colsumsq) {
  int b = blockIdx.x, t = threadIdx.x;
  if (b < 256) {
    wpre_t[b * 256 + t] = f2bf(W_pre[t * 256 + b]);
    if (b == 0) { colsum[t] = 0.f; colsumsq[t] = 0.f; }
  } else {
    int n = b - 256;
    wop_t[n * 256 + t] = f2bf(W_op[t * 256 + n]);
  }
}

// ---------------------------------------------------------------------------
// bf16 MFMA GEMM: C = A[M,256] @ B[256,256], Bt transposed [n][k].
// 128x256 tile, BK=64, 4 waves (2x2, each 64r x 128c), XOR-swizzled LDS.
// MODE 0: A is fp32 (converted in staging); C bf16 raw + column sum/sumsq
// MODE 1: A is bf16; C fp32 = relu((1-beta)*S + beta*(A@B)), S bf16
// ---------------------------------------------------------------------------
template<int MODE>
__global__ __launch_bounds__(256) void gemm_bf16_k(
    const void* __restrict__ Ain,
    const unsigned short* __restrict__ Bt,   // [256][256] bf16, Bt[n][k]
    void* __restrict__ Cout,                 // MODE0: bf16; MODE1: float
    const unsigned short* __restrict__ S,    // MODE1: residual bf16
    float* __restrict__ colsum,
    float* __restrict__ colsumsq,
    int M) {
  __shared__ unsigned short Al[128 * 64];    // 16 KB, row stride 128 B
  __shared__ unsigned short Bl[256 * 64];    // 32 KB
  __shared__ float cs[4][128], cq[4][128];   // MODE0 column-stat reduction

  const int t    = threadIdx.x;
  const int lane = t & 63;
  const int wid  = t >> 6;
  const int wr   = wid >> 1;                 // wave row (0/1): rows wr*64..+63
  const int wc   = wid & 1;                  // wave col (0/1): cols wc*128..+127
  const int row0 = blockIdx.x * 128;

  f32x4 acc[4][8] = {};

  const int srow = t & 127;                  // A staging row
  const int sseg = t >> 7;                   // A staging k-half (32 k each)
  const int arow = row0 + srow;
  const bool aok = arow < M;
  const int swzA = (srow & 7) << 4;
  const int swzB = (t & 7) << 4;

  for (int ks = 0; ks < 4; ++ks) {
    if (ks) __syncthreads();
    const int k0 = ks * 64;
    // ---- stage A (zero-pad OOB rows): thread -> half-row, 4x16B chunks ----
    if (MODE == 0) {
      const float* src = (const float*)Ain + (size_t)arow * 256 + k0 + sseg * 32;
#pragma unroll
      for (int c = 0; c < 4; ++c) {
        int byteoff = srow * 128 + ((sseg * 64 + c * 16) ^ swzA);
        bf16x8 v = {};
        if (aok) {
          f32x4 p = __builtin_nontemporal_load((const f32x4*)(src + c * 8));
          f32x4 q = __builtin_nontemporal_load((const f32x4*)(src + c * 8 + 4));
          v[0] = (short)f2bf(p.x); v[1] = (short)f2bf(p.y);
          v[2] = (short)f2bf(p.z); v[3] = (short)f2bf(p.w);
          v[4] = (short)f2bf(q.x); v[5] = (short)f2bf(q.y);
          v[6] = (short)f2bf(q.z); v[7] = (short)f2bf(q.w);
        }
        *(bf16x8*)((char*)Al + byteoff) = v;
      }
    } else {
      const unsigned short* src = (const unsigned short*)Ain + (size_t)arow * 256 + k0 + sseg * 32;
#pragma unroll
      for (int c = 0; c < 4; ++c) {
        int byteoff = srow * 128 + ((sseg * 64 + c * 16) ^ swzA);
        bf16x8 v = {};
        if (aok) v = *(const bf16x8*)(src + c * 8);
        *(bf16x8*)((char*)Al + byteoff) = v;
      }
    }
    // ---- stage B: thread -> full row t (256 rows), 8x16B chunks ----
    {
      const unsigned short* src = Bt + (size_t)t * 256 + k0;
#pragma unroll
      for (int c = 0; c < 8; ++c) {
        int byteoff = t * 128 + ((c * 16) ^ swzB);
        *(bf16x8*)((char*)Bl + byteoff) = *(const bf16x8*)(src + c * 8);
      }
    }
    __syncthreads();
    // ---- compute: 2 k-slices x 32 MFMA ----
#pragma unroll
    for (int kk = 0; kk < 2; ++kk) {
      const int koff = kk * 64 + ((lane >> 4) * 16);   // byte offset in row
      bf16x8 af[4], bfr[8];
#pragma unroll
      for (int m = 0; m < 4; ++m) {
        int row = wr * 64 + m * 16 + (lane & 15);
        af[m] = *(const bf16x8*)((char*)Al + row * 128 + (koff ^ ((row & 7) << 4)));
      }
#pragma unroll
      for (int n = 0; n < 8; ++n) {
        int nr = wc * 128 + n * 16 + (lane & 15);
        bfr[n] = *(const bf16x8*)((char*)Bl + nr * 128 + (koff ^ ((nr & 7) << 4)));
      }
#pragma unroll
      for (int m = 0; m < 4; ++m)
#pragma unroll
        for (int n = 0; n < 8; ++n)
          acc[m][n] = __builtin_amdgcn_mfma_f32_16x16x32_bf16(af[m], bfr[n], acc[m][n], 0, 0, 0);
    }
  }

  // ---- MODE 0: column sum / sumsq (OOB rows contributed exact zeros) ----
  if (MODE == 0) {
#pragma unroll
    for (int n = 0; n < 8; ++n) {
      float s = 0.f, q = 0.f;
#pragma unroll
      for (int m = 0; m < 4; ++m)
#pragma unroll
        for (int r = 0; r < 4; ++r) {
          float v = acc[m][n][r];
          s += v; q += v * v;
        }
      s += __shfl_xor(s, 16); s += __shfl_xor(s, 32);
      q += __shfl_xor(q, 16); q += __shfl_xor(q, 32);
      if (lane < 16) { cs[wid][n * 16 + lane] = s; cq[wid][n * 16 + lane] = q; }
    }
    __syncthreads();
    {
      int wcg = t >> 7;                      // column half (0/1)
      int lc  = t & 127;
      atomicAdd(&colsum[t],   cs[wcg][lc] + cs[wcg + 2][lc]);
      atomicAdd(&colsumsq[t], cq[wcg][lc] + cq[wcg + 2][lc]);
    }
  }

  // ---- store (C/D layout: col=lane&15, row=(lane>>4)*4+r) ----
#pragma unroll
  for (int m = 0; m < 4; ++m) {
    int rbase = row0 + wr * 64 + m * 16 + (lane >> 4) * 4;
#pragma unroll
    for (int r = 0; r < 4; ++r) {
      int row = rbase + r;
      if (row < M) {
#pragma unroll
        for (int n = 0; n < 8; ++n) {
          int col = wc * 128 + n * 16 + (lane & 15);
          float v = acc[m][n][r];
          if (MODE == 0) {
            ((unsigned short*)Cout)[(size_t)row * 256 + col] = f2bf(v);
          } else {
            float s = bf2f(S[(size_t)row * 256 + col]);
            float o = fmaxf((1.f - kBeta) * s + kBeta * v, 0.f);
            __builtin_nontemporal_store(o, (float*)Cout + (size_t)row * 256 + col);
          }
        }
      }
    }
  }
}

// ---------------------------------------------------------------------------
__global__ __launch_bounds__(256) void bn_finalize_k(const float* __restrict__ colsum,
                                                     const float* __restrict__ colsumsq,
                                                     const float* __restrict__ gamma,
                                                     const float* __restrict__ beta_bn,
                                                     float* __restrict__ scale,
                                                     float* __restrict__ shift) {
  int j = threadIdx.x;
  float inv_n = 1.0f / (float)NNODES;
  float mu  = colsum[j] * inv_n;
  float var = colsumsq[j] * inv_n - mu * mu;
  float rstd = rsqrtf(var + kBnEps);
  float sc = gamma[j] * rstd;
  scale[j] = sc;
  shift[j] = beta_bn[j] - mu * sc;
}

// ---------------------------------------------------------------------------
// CSR build: degree histogram -> 3-phase parallel scan -> bucket src ids
// ---------------------------------------------------------------------------
__global__ __launch_bounds__(256) void hist_k(const int* __restrict__ ei,
                                              int* __restrict__ deg) {
  // dst half of edge_index, vectorized int4
  const int4* dst4 = (const int4*)(ei + NEDGES);
  const int n4 = NEDGES / 4;
  int stride = gridDim.x * blockDim.x;
  for (int i = blockIdx.x * blockDim.x + threadIdx.x; i < n4; i += stride) {
    int4 d = dst4[i];
    atomicAdd(&deg[d.x], 1);
    atomicAdd(&deg[d.y], 1);
    atomicAdd(&deg[d.z], 1);
    atomicAdd(&deg[d.w], 1);
  }
}

__global__ __launch_bounds__(256) void scanA_k(const int* __restrict__ deg,
                                               int* __restrict__ rowptr,
                                               int* __restrict__ blocksum) {
  __shared__ int sh[256];
  const int t = threadIdx.x;
  const int idx = blockIdx.x * 256 + t;
  int v = (idx < NNODES) ? deg[idx] : 0;
  sh[t] = v;
  __syncthreads();
  for (int off = 1; off < 256; off <<= 1) {
    int x = (t >= off) ? sh[t - off] : 0;
    __syncthreads();
    sh[t] += x;
    __syncthreads();
  }
  if (idx < NNODES) rowptr[idx] = sh[t] - v;      // exclusive within block
  if (t == 255) blocksum[blockIdx.x] = sh[255];
}

__global__ __launch_bounds__(256) void scanB_k(const int* __restrict__ blocksum,
                                               int* __restrict__ blockoff,
                                               int* __restrict__ rowptr) {
  __shared__ int sh[256];
  const int t = threadIdx.x;
  int v = (t < NB_SCAN) ? blocksum[t] : 0;
  sh[t] = v;
  __syncthreads();
  for (int off = 1; off < 256; off <<= 1) {
    int x = (t >= off) ? sh[t - off] : 0;
    __syncthreads();
    sh[t] += x;
    __syncthreads();
  }
  blockoff[t] = sh[t] - v;                        // exclusive block offset
  if (t == 255) rowptr[NNODES] = sh[255];         // grand total (=NEDGES)
}

// finalize rowptr and seed the fill cursor with absolute positions
__global__ __launch_bounds__(256) void scanC_k(int* __restrict__ rowptr,
                                               const int* __restrict__ blockoff,
                                               int* __restrict__ cursor) {
  const int idx = blockIdx.x * 256 + threadIdx.x;
  if (idx < NNODES) {
    int rp = rowptr[idx] + blockoff[blockIdx.x];
    rowptr[idx] = rp;
    cursor[idx] = rp;
  }
}

__global__ __launch_bounds__(256) void fill_k(const int* __restrict__ ei,
                                              int* __restrict__ cursor,
                                              int* __restrict__ esrc) {
  int stride = gridDim.x * blockDim.x;
  for (int e = blockIdx.x * blockDim.x + threadIdx.x; e < NEDGES; e += stride) {
    int d = ei[NEDGES + e];
    int pos = atomicAdd(&cursor[d], 1);           // absolute slot
    esrc[pos] = ei[e];
  }
}

// ---------------------------------------------------------------------------
// Gather-sum per destination node with FUSED BatchNorm+ReLU on each gathered
// row, then GCNII support mix. Half-wave (32 lanes x 16B) per node; gathers
// unrolled x4 for ILP. x0 loads and supp stores are non-temporal so the hot
// h array keeps the L2/L3 capacity.
// ---------------------------------------------------------------------------
__global__ __launch_bounds__(256) void agg_bn_support_k(
    const unsigned short* __restrict__ hb,   // [N][256] raw bf16
    const int* __restrict__ rowptr,
    const int* __restrict__ esrc,
    const float* __restrict__ x0,
    const float* __restrict__ scale,
    const float* __restrict__ shift,
    unsigned short* __restrict__ supp_bf) {
  const int hw   = threadIdx.x >> 5;         // half-wave in block (0..7)
  const int lane = threadIdx.x & 31;
  const int d    = blockIdx.x * 8 + hw;      // grid sized exactly: no guard needed
  const int off  = lane * 8;                 // 8 bf16 elems = 16 B per lane

  float sc[8], sh[8];
  *(float4*)&sc[0] = *(const float4*)(scale + off);
  *(float4*)&sc[4] = *(const float4*)(scale + off + 4);
  *(float4*)&sh[0] = *(const float4*)(shift + off);
  *(float4*)&sh[4] = *(const float4*)(shift + off + 4);

  const int beg = rowptr[d];
  const int end = rowptr[d + 1];
  float acc[8] = {0.f, 0.f, 0.f, 0.f, 0.f, 0.f, 0.f, 0.f};

  int e = beg;
  for (; e + 3 < end; e += 4) {
    int s0 = esrc[e], s1 = esrc[e + 1], s2 = esrc[e + 2], s3 = esrc[e + 3];
    bf16x8 v0 = *(const bf16x8*)(hb + (size_t)s0 * HIDDIM + off);
    bf16x8 v1 = *(const bf16x8*)(hb + (size_t)s1 * HIDDIM + off);
    bf16x8 v2 = *(const bf16x8*)(hb + (size_t)s2 * HIDDIM + off);
    bf16x8 v3 = *(const bf16x8*)(hb + (size_t)s3 * HIDDIM + off);
#pragma unroll
    for (int j = 0; j < 8; ++j) {
      acc[j] += fmaxf(fmaf(bf2f((unsigned short)v0[j]), sc[j], sh[j]), 0.f)
              + fmaxf(fmaf(bf2f((unsigned short)v1[j]), sc[j], sh[j]), 0.f)
              + fmaxf(fmaf(bf2f((unsigned short)v2[j]), sc[j], sh[j]), 0.f)
              + fmaxf(fmaf(bf2f((unsigned short)v3[j]), sc[j], sh[j]), 0.f);
    }
  }
  for (; e < end; ++e) {
    int s0 = esrc[e];
    bf16x8 v0 = *(const bf16x8*)(hb + (size_t)s0 * HIDDIM + off);
#pragma unroll
    for (int j = 0; j < 8; ++j)
      acc[j] += fmaxf(fmaf(bf2f((unsigned short)v0[j]), sc[j], sh[j]), 0.f);
  }

  // self term + initial residual (x0 non-temporal: no reuse)
  bf16x8 vd = *(const bf16x8*)(hb + (size_t)d * HIDDIM + off);
  f32x4 xa = __builtin_nontemporal_load((const f32x4*)(x0 + (size_t)d * HIDDIM + off));
  f32x4 xb = __builtin_nontemporal_load((const f32x4*)(x0 + (size_t)d * HIDDIM + off + 4));
  float xs[8] = {xa.x, xa.y, xa.z, xa.w, xb.x, xb.y, xb.z, xb.w};
  bf16x8 o;
#pragma unroll
  for (int j = 0; j < 8; ++j) {
    float hv = fmaxf(fmaf(bf2f((unsigned short)vd[j]), sc[j], sh[j]), 0.f);
    o[j] = (short)f2bf((1.f - kAlpha) * (hv + acc[j]) + kAlpha * xs[j]);
  }
  __builtin_nontemporal_store(o, (bf16x8*)(supp_bf + (size_t)d * HIDDIM + off));
}

// ---------------------------------------------------------------------------
extern "C" void kernel_launch(void* const* d_in, const int* in_sizes, int n_in,
                              void* d_out, int out_size, void* d_ws, size_t ws_size,
                              hipStream_t stream) {
  // inputs: s0, s1, x_0, W_pre, gamma, beta_bn, W_op, edge_index, drop_prob, training
  const float* s1    = (const float*)d_in[1];
  const float* x0    = (const float*)d_in[2];
  const float* W_pre = (const float*)d_in[3];
  const float* gamma = (const float*)d_in[4];
  const float* betab = (const float*)d_in[5];
  const float* W_op  = (const float*)d_in[6];
  const int*   ei    = (const int*)d_in[7];
  float* out = (float*)d_out;

  const size_t NH = (size_t)NNODES * HIDDIM;            // 12.8M elements
  unsigned short* hbf   = (unsigned short*)d_ws;        // 25.6 MB (raw bf16 h)
  unsigned short* supbf = hbf + NH;                     // 25.6 MB
  float* colsum   = (float*)(supbf + NH);               // 256
  float* colsumsq = colsum + HIDDIM;
  float* scale    = colsumsq + HIDDIM;
  float* shift    = scale + HIDDIM;
  unsigned short* wpre_t = (unsigned short*)(shift + HIDDIM);  // 128 KB
  unsigned short* wop_t  = wpre_t + 65536;              // 128 KB
  int* deg      = (int*)(wop_t + 65536);                // 50000
  int* cursor   = deg + NNODES;                         // 50000
  int* rowptr   = cursor + NNODES;                      // 50001
  int* esrc     = rowptr + (NNODES + 1);                // 800000
  int* blocksum = esrc + NEDGES;                        // 256
  int* blockoff = blocksum + 256;                       // 256

  hipMemsetAsync(deg, 0, NNODES * sizeof(int), stream);

  prep_k<<<512, 256, 0, stream>>>(W_pre, W_op, wpre_t, wop_t, colsum, colsumsq);

  // CSR build
  hist_k<<<784, 256, 0, stream>>>(ei, deg);
  scanA_k<<<NB_SCAN, 256, 0, stream>>>(deg, rowptr, blocksum);
  scanB_k<<<1, 256, 0, stream>>>(blocksum, blockoff, rowptr);
  scanC_k<<<NB_SCAN, 256, 0, stream>>>(rowptr, blockoff, cursor);
  fill_k<<<1024, 256, 0, stream>>>(ei, cursor, esrc);

  // GEMM1 (fp32 A converted in staging) -> raw bf16 h + BN stats
  const int gx = (NNODES + 127) / 128;
  gemm_bf16_k<0><<<gx, 256, 0, stream>>>(s1, wpre_t, hbf, nullptr, colsum, colsumsq, NNODES);
  bn_finalize_k<<<1, HIDDIM, 0, stream>>>(colsum, colsumsq, gamma, betab, scale, shift);

  // gather + fused BN/ReLU + support mix
  agg_bn_support_k<<<(NNODES + 7) / 8, 256, 0, stream>>>(hbf, rowptr, esrc, x0,
                                                         scale, shift, supbf);

  // GEMM2 + GCNII epilogue
  gemm_bf16_k<1><<<gx, 256, 0, stream>>>(supbf, wop_t, out, supbf, nullptr, nullptr, NNODES);
}

// Round 8
// 243.324 us; speedup vs baseline: 1.0445x; 1.0445x over previous
//
#include <hip/hip_runtime.h>

#define NNODES 50000
#define NEDGES 800000
#define HIDDIM 256
#define NB_SCAN 196   // ceil(NNODES/256)

constexpr float kAlpha = 0.1f;
constexpr float kBnEps = 1e-5f;
constexpr float kBeta  = 0.40546510810816438198f;   // log(1.5)

typedef __attribute__((ext_vector_type(8))) short  bf16x8;   // 8 bf16 in 4 VGPRs
typedef __attribute__((ext_vector_type(4))) float  f32x4;

static __device__ __forceinline__ unsigned short f2bf(float f) {
  unsigned u = __float_as_uint(f);
  u = (u + 0x7FFFu + ((u >> 16) & 1u)) >> 16;      // RTNE
  return (unsigned short)u;
}
static __device__ __forceinline__ float bf2f(unsigned short h) {
  return __uint_as_float(((unsigned)h) << 16);
}

// ---------------------------------------------------------------------------
// prep: both weight transposes (fp32 [k][n] -> bf16 [n][k]) + zero BN stats
// ---------------------------------------------------------------------------
__global__ __launch_bounds__(256) void prep_k(const float* __restrict__ W_pre,
                                              const float* __restrict__ W_op,
                                              unsigned short* __restrict__ wpre_t,
                                              unsigned short* __restrict__ wop_t,
                                              float* __restrict__ colsum,
                                              float* __restrict__ colsumsq) {
  int b = blockIdx.x, t = threadIdx.x;
  if (b < 256) {
    wpre_t[b * 256 + t] = f2bf(W_pre[t * 256 + b]);
    if (b == 0) { colsum[t] = 0.f; colsumsq[t] = 0.f; }
  } else {
    int n = b - 256;
    wop_t[n * 256 + t] = f2bf(W_op[t * 256 + n]);
  }
}

// ---------------------------------------------------------------------------
// bf16 MFMA GEMM: C = A[M,256] @ B[256,256], Bt transposed [n][k].
// 128x256 tile, BK=64, 4 waves (2x2, each 64r x 128c), XOR-swizzled LDS,
// reg-staged double buffer: K-step k+1 global loads issued before the MFMAs
// of step k so HBM latency hides under compute.
// MODE 0: A is fp32 (converted in staging); C bf16 raw + column sum/sumsq
// MODE 1: A is bf16; C fp32 = relu((1-beta)*S + beta*(A@B)), S bf16
// ---------------------------------------------------------------------------
template<int MODE>
__global__ __launch_bounds__(256) void gemm_bf16_k(
    const void* __restrict__ Ain,
    const unsigned short* __restrict__ Bt,   // [256][256] bf16, Bt[n][k]
    void* __restrict__ Cout,                 // MODE0: bf16; MODE1: float
    const unsigned short* __restrict__ S,    // MODE1: residual bf16
    float* __restrict__ colsum,
    float* __restrict__ colsumsq,
    int M) {
  __shared__ unsigned short Al[128 * 64];    // 16 KB, row stride 128 B
  __shared__ unsigned short Bl[256 * 64];    // 32 KB
  __shared__ float cs[4][128], cq[4][128];   // MODE0 column-stat reduction

  const int t    = threadIdx.x;
  const int lane = t & 63;
  const int wid  = t >> 6;
  const int wr   = wid >> 1;                 // wave row (0/1): rows wr*64..+63
  const int wc   = wid & 1;                  // wave col (0/1): cols wc*128..+127
  const int row0 = blockIdx.x * 128;

  f32x4 acc[4][8] = {};

  const int srow = t & 127;                  // A staging row
  const int sseg = t >> 7;                   // A staging k-half (32 k each)
  const int arow = row0 + srow;
  const bool aok = arow < M;
  const int swzA = (srow & 7) << 4;
  const int swzB = (t & 7) << 4;

  // staging registers (double-buffer source)
  f32x4  pa[8];                              // MODE0: fp32 A half-row
  bf16x8 va[4];                              // MODE1: bf16 A half-row
  bf16x8 vb[8];                              // B full row

  auto load_step = [&](int ks) {
    const int k0 = ks * 64;
    if (MODE == 0) {
      const float* src = (const float*)Ain + (size_t)arow * 256 + k0 + sseg * 32;
      if (aok) {
#pragma unroll
        for (int c = 0; c < 8; ++c) pa[c] = *(const f32x4*)(src + c * 4);
      } else {
#pragma unroll
        for (int c = 0; c < 8; ++c) pa[c] = f32x4{0.f, 0.f, 0.f, 0.f};
      }
    } else {
      const unsigned short* src = (const unsigned short*)Ain + (size_t)arow * 256 + k0 + sseg * 32;
      if (aok) {
#pragma unroll
        for (int c = 0; c < 4; ++c) va[c] = *(const bf16x8*)(src + c * 8);
      } else {
#pragma unroll
        for (int c = 0; c < 4; ++c) va[c] = bf16x8{};
      }
    }
    const unsigned short* bsrc = Bt + (size_t)t * 256 + k0;
#pragma unroll
    for (int c = 0; c < 8; ++c) vb[c] = *(const bf16x8*)(bsrc + c * 8);
  };

  auto write_lds = [&]() {
#pragma unroll
    for (int c = 0; c < 4; ++c) {
      int byteoff = srow * 128 + ((sseg * 64 + c * 16) ^ swzA);
      bf16x8 v;
      if (MODE == 0) {
        f32x4 p = pa[c * 2], q = pa[c * 2 + 1];
        v[0] = (short)f2bf(p.x); v[1] = (short)f2bf(p.y);
        v[2] = (short)f2bf(p.z); v[3] = (short)f2bf(p.w);
        v[4] = (short)f2bf(q.x); v[5] = (short)f2bf(q.y);
        v[6] = (short)f2bf(q.z); v[7] = (short)f2bf(q.w);
      } else {
        v = va[c];
      }
      *(bf16x8*)((char*)Al + byteoff) = v;
    }
#pragma unroll
    for (int c = 0; c < 8; ++c) {
      int byteoff = t * 128 + ((c * 16) ^ swzB);
      *(bf16x8*)((char*)Bl + byteoff) = vb[c];
    }
  };

  load_step(0);
  for (int ks = 0; ks < 4; ++ks) {
    write_lds();
    __syncthreads();                         // LDS tile ready
    if (ks < 3) load_step(ks + 1);           // issue next-step loads (fly under MFMA)
    // ---- compute: 2 k-slices x 32 MFMA ----
#pragma unroll
    for (int kk = 0; kk < 2; ++kk) {
      const int koff = kk * 64 + ((lane >> 4) * 16);   // byte offset in row
      bf16x8 af[4], bfr[8];
#pragma unroll
      for (int m = 0; m < 4; ++m) {
        int row = wr * 64 + m * 16 + (lane & 15);
        af[m] = *(const bf16x8*)((char*)Al + row * 128 + (koff ^ ((row & 7) << 4)));
      }
#pragma unroll
      for (int n = 0; n < 8; ++n) {
        int nr = wc * 128 + n * 16 + (lane & 15);
        bfr[n] = *(const bf16x8*)((char*)Bl + nr * 128 + (koff ^ ((nr & 7) << 4)));
      }
#pragma unroll
      for (int m = 0; m < 4; ++m)
#pragma unroll
        for (int n = 0; n < 8; ++n)
          acc[m][n] = __builtin_amdgcn_mfma_f32_16x16x32_bf16(af[m], bfr[n], acc[m][n], 0, 0, 0);
    }
    __syncthreads();                         // reads done before next write
  }

  // ---- MODE 0: column sum / sumsq (OOB rows contributed exact zeros) ----
  if (MODE == 0) {
#pragma unroll
    for (int n = 0; n < 8; ++n) {
      float s = 0.f, q = 0.f;
#pragma unroll
      for (int m = 0; m < 4; ++m)
#pragma unroll
        for (int r = 0; r < 4; ++r) {
          float v = acc[m][n][r];
          s += v; q += v * v;
        }
      s += __shfl_xor(s, 16); s += __shfl_xor(s, 32);
      q += __shfl_xor(q, 16); q += __shfl_xor(q, 32);
      if (lane < 16) { cs[wid][n * 16 + lane] = s; cq[wid][n * 16 + lane] = q; }
    }
    __syncthreads();
    {
      int wcg = t >> 7;                      // column half (0/1)
      int lc  = t & 127;
      atomicAdd(&colsum[t],   cs[wcg][lc] + cs[wcg + 2][lc]);
      atomicAdd(&colsumsq[t], cq[wcg][lc] + cq[wcg + 2][lc]);
    }
  }

  // ---- store (C/D layout: col=lane&15, row=(lane>>4)*4+r) ----
#pragma unroll
  for (int m = 0; m < 4; ++m) {
    int rbase = row0 + wr * 64 + m * 16 + (lane >> 4) * 4;
#pragma unroll
    for (int r = 0; r < 4; ++r) {
      int row = rbase + r;
      if (row < M) {
#pragma unroll
        for (int n = 0; n < 8; ++n) {
          int col = wc * 128 + n * 16 + (lane & 15);
          float v = acc[m][n][r];
          if (MODE == 0) {
            ((unsigned short*)Cout)[(size_t)row * 256 + col] = f2bf(v);
          } else {
            float s = bf2f(S[(size_t)row * 256 + col]);
            ((float*)Cout)[(size_t)row * 256 + col] =
                fmaxf((1.f - kBeta) * s + kBeta * v, 0.f);
          }
        }
      }
    }
  }
}

// ---------------------------------------------------------------------------
__global__ __launch_bounds__(256) void bn_finalize_k(const float* __restrict__ colsum,
                                                     const float* __restrict__ colsumsq,
                                                     const float* __restrict__ gamma,
                                                     const float* __restrict__ beta_bn,
                                                     float* __restrict__ scale,
                                                     float* __restrict__ shift) {
  int j = threadIdx.x;
  float inv_n = 1.0f / (float)NNODES;
  float mu  = colsum[j] * inv_n;
  float var = colsumsq[j] * inv_n - mu * mu;
  float rstd = rsqrtf(var + kBnEps);
  float sc = gamma[j] * rstd;
  scale[j] = sc;
  shift[j] = beta_bn[j] - mu * sc;
}

// ---------------------------------------------------------------------------
// CSR build: degree histogram -> 3-phase parallel scan -> bucket src ids
// ---------------------------------------------------------------------------
__global__ __launch_bounds__(256) void hist_k(const int* __restrict__ ei,
                                              int* __restrict__ deg) {
  const int4* dst4 = (const int4*)(ei + NEDGES);
  const int n4 = NEDGES / 4;
  int stride = gridDim.x * blockDim.x;
  for (int i = blockIdx.x * blockDim.x + threadIdx.x; i < n4; i += stride) {
    int4 d = dst4[i];
    atomicAdd(&deg[d.x], 1);
    atomicAdd(&deg[d.y], 1);
    atomicAdd(&deg[d.z], 1);
    atomicAdd(&deg[d.w], 1);
  }
}

__global__ __launch_bounds__(256) void scanA_k(const int* __restrict__ deg,
                                               int* __restrict__ rowptr,
                                               int* __restrict__ blocksum) {
  __shared__ int sh[256];
  const int t = threadIdx.x;
  const int idx = blockIdx.x * 256 + t;
  int v = (idx < NNODES) ? deg[idx] : 0;
  sh[t] = v;
  __syncthreads();
  for (int off = 1; off < 256; off <<= 1) {
    int x = (t >= off) ? sh[t - off] : 0;
    __syncthreads();
    sh[t] += x;
    __syncthreads();
  }
  if (idx < NNODES) rowptr[idx] = sh[t] - v;      // exclusive within block
  if (t == 255) blocksum[blockIdx.x] = sh[255];
}

__global__ __launch_bounds__(256) void scanB_k(const int* __restrict__ blocksum,
                                               int* __restrict__ blockoff,
                                               int* __restrict__ rowptr) {
  __shared__ int sh[256];
  const int t = threadIdx.x;
  int v = (t < NB_SCAN) ? blocksum[t] : 0;
  sh[t] = v;
  __syncthreads();
  for (int off = 1; off < 256; off <<= 1) {
    int x = (t >= off) ? sh[t - off] : 0;
    __syncthreads();
    sh[t] += x;
    __syncthreads();
  }
  blockoff[t] = sh[t] - v;                        // exclusive block offset
  if (t == 255) rowptr[NNODES] = sh[255];         // grand total (=NEDGES)
}

// finalize rowptr and seed the fill cursor with absolute positions
__global__ __launch_bounds__(256) void scanC_k(int* __restrict__ rowptr,
                                               const int* __restrict__ blockoff,
                                               int* __restrict__ cursor) {
  const int idx = blockIdx.x * 256 + threadIdx.x;
  if (idx < NNODES) {
    int rp = rowptr[idx] + blockoff[blockIdx.x];
    rowptr[idx] = rp;
    cursor[idx] = rp;
  }
}

__global__ __launch_bounds__(256) void fill_k(const int* __restrict__ ei,
                                              int* __restrict__ cursor,
                                              int* __restrict__ esrc) {
  int stride = gridDim.x * blockDim.x;
  for (int e = blockIdx.x * blockDim.x + threadIdx.x; e < NEDGES; e += stride) {
    int d = ei[NEDGES + e];
    int pos = atomicAdd(&cursor[d], 1);           // absolute slot
    esrc[pos] = ei[e];
  }
}

// ---------------------------------------------------------------------------
// Gather-sum per destination node with FUSED BatchNorm+ReLU on each gathered
// row, then GCNII support mix. Half-wave (32 lanes x 16B) per node; gathers
// unrolled x8 for ILP. x0 loads and supp stores are non-temporal so the hot
// h array keeps the L2/L3 capacity.
// ---------------------------------------------------------------------------
__global__ __launch_bounds__(256) void agg_bn_support_k(
    const unsigned short* __restrict__ hb,   // [N][256] raw bf16
    const int* __restrict__ rowptr,
    const int* __restrict__ esrc,
    const float* __restrict__ x0,
    const float* __restrict__ scale,
    const float* __restrict__ shift,
    unsigned short* __restrict__ supp_bf) {
  const int hw   = threadIdx.x >> 5;         // half-wave in block (0..7)
  const int lane = threadIdx.x & 31;
  const int d    = blockIdx.x * 8 + hw;      // grid sized exactly: no guard needed
  const int off  = lane * 8;                 // 8 bf16 elems = 16 B per lane

  float sc[8], sh[8];
  *(float4*)&sc[0] = *(const float4*)(scale + off);
  *(float4*)&sc[4] = *(const float4*)(scale + off + 4);
  *(float4*)&sh[0] = *(const float4*)(shift + off);
  *(float4*)&sh[4] = *(const float4*)(shift + off + 4);

  const int beg = rowptr[d];
  const int end = rowptr[d + 1];
  float acc[8] = {0.f, 0.f, 0.f, 0.f, 0.f, 0.f, 0.f, 0.f};

  int e = beg;
  for (; e + 7 < end; e += 8) {
    bf16x8 v[8];
#pragma unroll
    for (int u = 0; u < 8; ++u)
      v[u] = *(const bf16x8*)(hb + (size_t)esrc[e + u] * HIDDIM + off);
#pragma unroll
    for (int u = 0; u < 8; ++u)
#pragma unroll
      for (int j = 0; j < 8; ++j)
        acc[j] += fmaxf(fmaf(bf2f((unsigned short)v[u][j]), sc[j], sh[j]), 0.f);
  }
  for (; e + 3 < end; e += 4) {
    bf16x8 v[4];
#pragma unroll
    for (int u = 0; u < 4; ++u)
      v[u] = *(const bf16x8*)(hb + (size_t)esrc[e + u] * HIDDIM + off);
#pragma unroll
    for (int u = 0; u < 4; ++u)
#pragma unroll
      for (int j = 0; j < 8; ++j)
        acc[j] += fmaxf(fmaf(bf2f((unsigned short)v[u][j]), sc[j], sh[j]), 0.f);
  }
  for (; e < end; ++e) {
    bf16x8 v0 = *(const bf16x8*)(hb + (size_t)esrc[e] * HIDDIM + off);
#pragma unroll
    for (int j = 0; j < 8; ++j)
      acc[j] += fmaxf(fmaf(bf2f((unsigned short)v0[j]), sc[j], sh[j]), 0.f);
  }

  // self term + initial residual (x0 non-temporal: no reuse)
  bf16x8 vd = *(const bf16x8*)(hb + (size_t)d * HIDDIM + off);
  f32x4 xa = __builtin_nontemporal_load((const f32x4*)(x0 + (size_t)d * HIDDIM + off));
  f32x4 xb = __builtin_nontemporal_load((const f32x4*)(x0 + (size_t)d * HIDDIM + off + 4));
  float xs[8] = {xa.x, xa.y, xa.z, xa.w, xb.x, xb.y, xb.z, xb.w};
  bf16x8 o;
#pragma unroll
  for (int j = 0; j < 8; ++j) {
    float hv = fmaxf(fmaf(bf2f((unsigned short)vd[j]), sc[j], sh[j]), 0.f);
    o[j] = (short)f2bf((1.f - kAlpha) * (hv + acc[j]) + kAlpha * xs[j]);
  }
  __builtin_nontemporal_store(o, (bf16x8*)(supp_bf + (size_t)d * HIDDIM + off));
}

// ---------------------------------------------------------------------------
extern "C" void kernel_launch(void* const* d_in, const int* in_sizes, int n_in,
                              void* d_out, int out_size, void* d_ws, size_t ws_size,
                              hipStream_t stream) {
  // inputs: s0, s1, x_0, W_pre, gamma, beta_bn, W_op, edge_index, drop_prob, training
  const float* s1    = (const float*)d_in[1];
  const float* x0    = (const float*)d_in[2];
  const float* W_pre = (const float*)d_in[3];
  const float* gamma = (const float*)d_in[4];
  const float* betab = (const float*)d_in[5];
  const float* W_op  = (const float*)d_in[6];
  const int*   ei    = (const int*)d_in[7];
  float* out = (float*)d_out;

  const size_t NH = (size_t)NNODES * HIDDIM;            // 12.8M elements
  unsigned short* hbf   = (unsigned short*)d_ws;        // 25.6 MB (raw bf16 h)
  unsigned short* supbf = hbf + NH;                     // 25.6 MB
  float* colsum   = (float*)(supbf + NH);               // 256
  float* colsumsq = colsum + HIDDIM;
  float* scale    = colsumsq + HIDDIM;
  float* shift    = scale + HIDDIM;
  unsigned short* wpre_t = (unsigned short*)(shift + HIDDIM);  // 128 KB
  unsigned short* wop_t  = wpre_t + 65536;              // 128 KB
  int* deg      = (int*)(wop_t + 65536);                // 50000
  int* cursor   = deg + NNODES;                         // 50000
  int* rowptr   = cursor + NNODES;                      // 50001
  int* esrc     = rowptr + (NNODES + 1);                // 800000
  int* blocksum = esrc + NEDGES;                        // 256
  int* blockoff = blocksum + 256;                       // 256

  hipMemsetAsync(deg, 0, NNODES * sizeof(int), stream);

  prep_k<<<512, 256, 0, stream>>>(W_pre, W_op, wpre_t, wop_t, colsum, colsumsq);

  // CSR build
  hist_k<<<784, 256, 0, stream>>>(ei, deg);
  scanA_k<<<NB_SCAN, 256, 0, stream>>>(deg, rowptr, blocksum);
  scanB_k<<<1, 256, 0, stream>>>(blocksum, blockoff, rowptr);
  scanC_k<<<NB_SCAN, 256, 0, stream>>>(rowptr, blockoff, cursor);
  fill_k<<<1024, 256, 0, stream>>>(ei, cursor, esrc);

  // GEMM1 (fp32 A converted in staging) -> raw bf16 h + BN stats
  const int gx = (NNODES + 127) / 128;
  gemm_bf16_k<0><<<gx, 256, 0, stream>>>(s1, wpre_t, hbf, nullptr, colsum, colsumsq, NNODES);
  bn_finalize_k<<<1, HIDDIM, 0, stream>>>(colsum, colsumsq, gamma, betab, scale, shift);

  // gather + fused BN/ReLU + support mix
  agg_bn_support_k<<<(NNODES + 7) / 8, 256, 0, stream>>>(hbf, rowptr, esrc, x0,
                                                         scale, shift, supbf);

  // GEMM2 + GCNII epilogue
  gemm_bf16_k<1><<<gx, 256, 0, stream>>>(supbf, wop_t, out, supbf, nullptr, nullptr, NNODES);
}

// Round 9
// 230.793 us; speedup vs baseline: 1.1012x; 1.0543x over previous
//
#include <hip/hip_runtime.h>

#define NNODES 50000
#define NEDGES 800000
#define HIDDIM 256
#define NB_SCAN 196   // ceil(NNODES/256)

constexpr float kAlpha = 0.1f;
constexpr float kBnEps = 1e-5f;
constexpr float kBeta  = 0.40546510810816438198f;   // log(1.5)

typedef __attribute__((ext_vector_type(8))) short  bf16x8;   // 8 bf16 in 4 VGPRs
typedef __attribute__((ext_vector_type(4))) float  f32x4;

typedef __attribute__((address_space(1))) const unsigned int gu32;  // global
typedef __attribute__((address_space(3))) unsigned int       lu32;  // LDS

static __device__ __forceinline__ unsigned short f2bf(float f) {
  unsigned u = __float_as_uint(f);
  u = (u + 0x7FFFu + ((u >> 16) & 1u)) >> 16;      // RTNE
  return (unsigned short)u;
}
static __device__ __forceinline__ float bf2f(unsigned short h) {
  return __uint_as_float(((unsigned)h) << 16);
}

// ---------------------------------------------------------------------------
// prep: weight transposes (fp32 [k][n] -> bf16 [n][k]) + zero BN stats + deg
// ---------------------------------------------------------------------------
__global__ __launch_bounds__(256) void prep_k(const float* __restrict__ W_pre,
                                              const float* __restrict__ W_op,
                                              unsigned short* __restrict__ wpre_t,
                                              unsigned short* __restrict__ wop_t,
                                              float* __restrict__ colsum,
                                              float* __restrict__ colsumsq,
                                              int* __restrict__ deg) {
  int b = blockIdx.x, t = threadIdx.x;
  if (b < 256) {
    wpre_t[b * 256 + t] = f2bf(W_pre[t * 256 + b]);
    if (b == 0) { colsum[t] = 0.f; colsumsq[t] = 0.f; }
  } else {
    int n = b - 256;
    wop_t[n * 256 + t] = f2bf(W_op[t * 256 + n]);
  }
  if (b < NB_SCAN) {
    int idx = b * 256 + t;
    if (idx < NNODES) deg[idx] = 0;
  }
}

// ---------------------------------------------------------------------------
// bf16 MFMA GEMM: C = A[M,256] @ B[256,256], Bt transposed [n][k].
// 128x256 tile, BK=64, 4 waves (2x2, each 64r x 128c), XOR-swizzled LDS.
// Staging via global_load_lds (linear LDS dest + inverse-swizzled source;
// read side keeps the same XOR -> identical placement as reg-staged path).
// MODE 0: A fp32 (reg-staged + converted); C bf16 raw + column sum/sumsq
// MODE 1: A bf16 (global_load_lds); C fp32 = relu((1-beta)*S + beta*(A@B))
// ---------------------------------------------------------------------------
template<int MODE>
__global__ __launch_bounds__(256) void gemm_bf16_k(
    const void* __restrict__ Ain,
    const unsigned short* __restrict__ Bt,   // [256][256] bf16, Bt[n][k]
    void* __restrict__ Cout,                 // MODE0: bf16; MODE1: float
    const unsigned short* __restrict__ S,    // MODE1: residual bf16
    float* __restrict__ colsum,
    float* __restrict__ colsumsq,
    int M) {
  __shared__ unsigned short Al[128 * 64];    // 16 KB, row stride 128 B
  __shared__ unsigned short Bl[256 * 64];    // 32 KB
  __shared__ float cs[4][128], cq[4][128];   // MODE0 column-stat reduction

  const int t    = threadIdx.x;
  const int lane = t & 63;
  const int wid  = t >> 6;
  const int wr   = wid >> 1;                 // wave row (0/1): rows wr*64..+63
  const int wc   = wid & 1;                  // wave col (0/1): cols wc*128..+127
  const int row0 = blockIdx.x * 128;

  f32x4 acc[4][8] = {};

  // reg-staging assignment (MODE 0 A)
  const int srow = t & 127;
  const int sseg = t >> 7;
  const int arow = row0 + srow;
  const bool aok = arow < M;
  const int swzA = (srow & 7) << 4;

  // global_load_lds lane decomposition: 1 issue = 1024 B = 8 rows x 128 B
  const int lrow = lane >> 3;                      // row within 8-row group
  const int lchk = lane & 7;                       // 16B chunk within row
  const int lsw  = (lchk * 16) ^ (lrow << 4);      // inverse-swizzled src offset

  for (int ks = 0; ks < 4; ++ks) {
    if (ks) __syncthreads();
    const int k0 = ks * 64;

    // ---- stage A ----
    if (MODE == 0) {
      const float* src = (const float*)Ain + (size_t)arow * 256 + k0 + sseg * 32;
#pragma unroll
      for (int c = 0; c < 4; ++c) {
        int byteoff = srow * 128 + ((sseg * 64 + c * 16) ^ swzA);
        bf16x8 v = {};
        if (aok) {
          float4 p = *(const float4*)(src + c * 8);
          float4 q = *(const float4*)(src + c * 8 + 4);
          v[0] = (short)f2bf(p.x); v[1] = (short)f2bf(p.y);
          v[2] = (short)f2bf(p.z); v[3] = (short)f2bf(p.w);
          v[4] = (short)f2bf(q.x); v[5] = (short)f2bf(q.y);
          v[6] = (short)f2bf(q.z); v[7] = (short)f2bf(q.w);
        }
        *(bf16x8*)((char*)Al + byteoff) = v;
      }
    } else {
      // 4 issues/wave: rows wid*32 + c*8 + lrow  (OOB rows read garbage inside
      // d_ws; results masked at store)
#pragma unroll
      for (int c = 0; c < 4; ++c) {
        int row = wid * 32 + c * 8 + lrow;
        const char* g = (const char*)Ain + ((size_t)(row0 + row) * 256 + k0) * 2 + lsw;
        char* l = (char*)Al + wid * 4096 + c * 1024 + lane * 16;
        __builtin_amdgcn_global_load_lds((gu32*)g, (lu32*)l, 16, 0, 0);
      }
    }
    // ---- stage B: 8 issues/wave, rows wid*64 + c*8 + lrow ----
#pragma unroll
    for (int c = 0; c < 8; ++c) {
      int row = wid * 64 + c * 8 + lrow;
      const char* g = (const char*)Bt + ((size_t)row * 256 + k0) * 2 + lsw;
      char* l = (char*)Bl + wid * 8192 + c * 1024 + lane * 16;
      __builtin_amdgcn_global_load_lds((gu32*)g, (lu32*)l, 16, 0, 0);
    }
    __syncthreads();                         // drains vmcnt before reads

    // ---- compute: 2 k-slices x 32 MFMA ----
#pragma unroll
    for (int kk = 0; kk < 2; ++kk) {
      const int koff = kk * 64 + ((lane >> 4) * 16);   // byte offset in row
      bf16x8 af[4], bfr[8];
#pragma unroll
      for (int m = 0; m < 4; ++m) {
        int row = wr * 64 + m * 16 + (lane & 15);
        af[m] = *(const bf16x8*)((char*)Al + row * 128 + (koff ^ ((row & 7) << 4)));
      }
#pragma unroll
      for (int n = 0; n < 8; ++n) {
        int nr = wc * 128 + n * 16 + (lane & 15);
        bfr[n] = *(const bf16x8*)((char*)Bl + nr * 128 + (koff ^ ((nr & 7) << 4)));
      }
#pragma unroll
      for (int m = 0; m < 4; ++m)
#pragma unroll
        for (int n = 0; n < 8; ++n)
          acc[m][n] = __builtin_amdgcn_mfma_f32_16x16x32_bf16(af[m], bfr[n], acc[m][n], 0, 0, 0);
    }
  }

  // ---- MODE 0: column sum / sumsq (OOB rows contributed exact zeros) ----
  if (MODE == 0) {
#pragma unroll
    for (int n = 0; n < 8; ++n) {
      float s = 0.f, q = 0.f;
#pragma unroll
      for (int m = 0; m < 4; ++m)
#pragma unroll
        for (int r = 0; r < 4; ++r) {
          float v = acc[m][n][r];
          s += v; q += v * v;
        }
      s += __shfl_xor(s, 16); s += __shfl_xor(s, 32);
      q += __shfl_xor(q, 16); q += __shfl_xor(q, 32);
      if (lane < 16) { cs[wid][n * 16 + lane] = s; cq[wid][n * 16 + lane] = q; }
    }
    __syncthreads();
    {
      int wcg = t >> 7;                      // column half (0/1)
      int lc  = t & 127;
      atomicAdd(&colsum[t],   cs[wcg][lc] + cs[wcg + 2][lc]);
      atomicAdd(&colsumsq[t], cq[wcg][lc] + cq[wcg + 2][lc]);
    }
  }

  // ---- store (C/D layout: col=lane&15, row=(lane>>4)*4+r) ----
#pragma unroll
  for (int m = 0; m < 4; ++m) {
    int rbase = row0 + wr * 64 + m * 16 + (lane >> 4) * 4;
#pragma unroll
    for (int r = 0; r < 4; ++r) {
      int row = rbase + r;
      if (row < M) {
#pragma unroll
        for (int n = 0; n < 8; ++n) {
          int col = wc * 128 + n * 16 + (lane & 15);
          float v = acc[m][n][r];
          if (MODE == 0) {
            ((unsigned short*)Cout)[(size_t)row * 256 + col] = f2bf(v);
          } else {
            float s = bf2f(S[(size_t)row * 256 + col]);
            ((float*)Cout)[(size_t)row * 256 + col] =
                fmaxf((1.f - kBeta) * s + kBeta * v, 0.f);
          }
        }
      }
    }
  }
}

// ---------------------------------------------------------------------------
__global__ __launch_bounds__(256) void bn_finalize_k(const float* __restrict__ colsum,
                                                     const float* __restrict__ colsumsq,
                                                     const float* __restrict__ gamma,
                                                     const float* __restrict__ beta_bn,
                                                     float* __restrict__ scale,
                                                     float* __restrict__ shift) {
  int j = threadIdx.x;
  float inv_n = 1.0f / (float)NNODES;
  float mu  = colsum[j] * inv_n;
  float var = colsumsq[j] * inv_n - mu * mu;
  float rstd = rsqrtf(var + kBnEps);
  float sc = gamma[j] * rstd;
  scale[j] = sc;
  shift[j] = beta_bn[j] - mu * sc;
}

// ---------------------------------------------------------------------------
// CSR build: degree histogram -> 3-phase parallel scan -> bucket src ids
// ---------------------------------------------------------------------------
__global__ __launch_bounds__(256) void hist_k(const int* __restrict__ ei,
                                              int* __restrict__ deg) {
  const int4* dst4 = (const int4*)(ei + NEDGES);
  const int n4 = NEDGES / 4;
  int stride = gridDim.x * blockDim.x;
  for (int i = blockIdx.x * blockDim.x + threadIdx.x; i < n4; i += stride) {
    int4 d = dst4[i];
    atomicAdd(&deg[d.x], 1);
    atomicAdd(&deg[d.y], 1);
    atomicAdd(&deg[d.z], 1);
    atomicAdd(&deg[d.w], 1);
  }
}

__global__ __launch_bounds__(256) void scanA_k(const int* __restrict__ deg,
                                               int* __restrict__ rowptr,
                                               int* __restrict__ blocksum) {
  __shared__ int sh[256];
  const int t = threadIdx.x;
  const int idx = blockIdx.x * 256 + t;
  int v = (idx < NNODES) ? deg[idx] : 0;
  sh[t] = v;
  __syncthreads();
  for (int off = 1; off < 256; off <<= 1) {
    int x = (t >= off) ? sh[t - off] : 0;
    __syncthreads();
    sh[t] += x;
    __syncthreads();
  }
  if (idx < NNODES) rowptr[idx] = sh[t] - v;      // exclusive within block
  if (t == 255) blocksum[blockIdx.x] = sh[255];
}

__global__ __launch_bounds__(256) void scanB_k(const int* __restrict__ blocksum,
                                               int* __restrict__ blockoff,
                                               int* __restrict__ rowptr) {
  __shared__ int sh[256];
  const int t = threadIdx.x;
  int v = (t < NB_SCAN) ? blocksum[t] : 0;
  sh[t] = v;
  __syncthreads();
  for (int off = 1; off < 256; off <<= 1) {
    int x = (t >= off) ? sh[t - off] : 0;
    __syncthreads();
    sh[t] += x;
    __syncthreads();
  }
  blockoff[t] = sh[t] - v;                        // exclusive block offset
  if (t == 255) rowptr[NNODES] = sh[255];         // grand total (=NEDGES)
}

// finalize rowptr and seed the fill cursor with absolute positions
__global__ __launch_bounds__(256) void scanC_k(int* __restrict__ rowptr,
                                               const int* __restrict__ blockoff,
                                               int* __restrict__ cursor) {
  const int idx = blockIdx.x * 256 + threadIdx.x;
  if (idx < NNODES) {
    int rp = rowptr[idx] + blockoff[blockIdx.x];
    rowptr[idx] = rp;
    cursor[idx] = rp;
  }
}

__global__ __launch_bounds__(256) void fill_k(const int* __restrict__ ei,
                                              int* __restrict__ cursor,
                                              int* __restrict__ esrc) {
  const int4* src4 = (const int4*)ei;
  const int4* dst4 = (const int4*)(ei + NEDGES);
  const int n4 = NEDGES / 4;
  int stride = gridDim.x * blockDim.x;
  for (int i = blockIdx.x * blockDim.x + threadIdx.x; i < n4; i += stride) {
    int4 s = src4[i];
    int4 d = dst4[i];
    esrc[atomicAdd(&cursor[d.x], 1)] = s.x;
    esrc[atomicAdd(&cursor[d.y], 1)] = s.y;
    esrc[atomicAdd(&cursor[d.z], 1)] = s.z;
    esrc[atomicAdd(&cursor[d.w], 1)] = s.w;
  }
}

// ---------------------------------------------------------------------------
// Gather-sum per destination node with FUSED BatchNorm+ReLU on each gathered
// row, then GCNII support mix. Half-wave (32 lanes x 16B) per node; gathers
// unrolled x4 (40 VGPR -> ~50% occupancy; x8 drops occupancy, no gain).
// x0 loads and supp stores non-temporal so the hot h array keeps L2/L3.
// ---------------------------------------------------------------------------
__global__ __launch_bounds__(256) void agg_bn_support_k(
    const unsigned short* __restrict__ hb,   // [N][256] raw bf16
    const int* __restrict__ rowptr,
    const int* __restrict__ esrc,
    const float* __restrict__ x0,
    const float* __restrict__ scale,
    const float* __restrict__ shift,
    unsigned short* __restrict__ supp_bf) {
  const int hw   = threadIdx.x >> 5;         // half-wave in block (0..7)
  const int lane = threadIdx.x & 31;
  const int d    = blockIdx.x * 8 + hw;      // grid sized exactly: no guard needed
  const int off  = lane * 8;                 // 8 bf16 elems = 16 B per lane

  float sc[8], sh[8];
  *(float4*)&sc[0] = *(const float4*)(scale + off);
  *(float4*)&sc[4] = *(const float4*)(scale + off + 4);
  *(float4*)&sh[0] = *(const float4*)(shift + off);
  *(float4*)&sh[4] = *(const float4*)(shift + off + 4);

  const int beg = rowptr[d];
  const int end = rowptr[d + 1];
  float acc[8] = {0.f, 0.f, 0.f, 0.f, 0.f, 0.f, 0.f, 0.f};

  int e = beg;
  for (; e + 3 < end; e += 4) {
    int s0 = esrc[e], s1 = esrc[e + 1], s2 = esrc[e + 2], s3 = esrc[e + 3];
    bf16x8 v0 = *(const bf16x8*)(hb + (size_t)s0 * HIDDIM + off);
    bf16x8 v1 = *(const bf16x8*)(hb + (size_t)s1 * HIDDIM + off);
    bf16x8 v2 = *(const bf16x8*)(hb + (size_t)s2 * HIDDIM + off);
    bf16x8 v3 = *(const bf16x8*)(hb + (size_t)s3 * HIDDIM + off);
#pragma unroll
    for (int j = 0; j < 8; ++j) {
      acc[j] += fmaxf(fmaf(bf2f((unsigned short)v0[j]), sc[j], sh[j]), 0.f)
              + fmaxf(fmaf(bf2f((unsigned short)v1[j]), sc[j], sh[j]), 0.f)
              + fmaxf(fmaf(bf2f((unsigned short)v2[j]), sc[j], sh[j]), 0.f)
              + fmaxf(fmaf(bf2f((unsigned short)v3[j]), sc[j], sh[j]), 0.f);
    }
  }
  for (; e < end; ++e) {
    int s0 = esrc[e];
    bf16x8 v0 = *(const bf16x8*)(hb + (size_t)s0 * HIDDIM + off);
#pragma unroll
    for (int j = 0; j < 8; ++j)
      acc[j] += fmaxf(fmaf(bf2f((unsigned short)v0[j]), sc[j], sh[j]), 0.f);
  }

  // self term + initial residual (x0 non-temporal: no reuse)
  bf16x8 vd = *(const bf16x8*)(hb + (size_t)d * HIDDIM + off);
  f32x4 xa = __builtin_nontemporal_load((const f32x4*)(x0 + (size_t)d * HIDDIM + off));
  f32x4 xb = __builtin_nontemporal_load((const f32x4*)(x0 + (size_t)d * HIDDIM + off + 4));
  float xs[8] = {xa.x, xa.y, xa.z, xa.w, xb.x, xb.y, xb.z, xb.w};
  bf16x8 o;
#pragma unroll
  for (int j = 0; j < 8; ++j) {
    float hv = fmaxf(fmaf(bf2f((unsigned short)vd[j]), sc[j], sh[j]), 0.f);
    o[j] = (short)f2bf((1.f - kAlpha) * (hv + acc[j]) + kAlpha * xs[j]);
  }
  __builtin_nontemporal_store(o, (bf16x8*)(supp_bf + (size_t)d * HIDDIM + off));
}

// ---------------------------------------------------------------------------
extern "C" void kernel_launch(void* const* d_in, const int* in_sizes, int n_in,
                              void* d_out, int out_size, void* d_ws, size_t ws_size,
                              hipStream_t stream) {
  // inputs: s0, s1, x_0, W_pre, gamma, beta_bn, W_op, edge_index, drop_prob, training
  const float* s1    = (const float*)d_in[1];
  const float* x0    = (const float*)d_in[2];
  const float* W_pre = (const float*)d_in[3];
  const float* gamma = (const float*)d_in[4];
  const float* betab = (const float*)d_in[5];
  const float* W_op  = (const float*)d_in[6];
  const int*   ei    = (const int*)d_in[7];
  float* out = (float*)d_out;

  const size_t NH = (size_t)NNODES * HIDDIM;            // 12.8M elements
  unsigned short* hbf   = (unsigned short*)d_ws;        // 25.6 MB (raw bf16 h)
  unsigned short* supbf = hbf + NH;                     // 25.6 MB
  float* colsum   = (float*)(supbf + NH);               // 256
  float* colsumsq = colsum + HIDDIM;
  float* scale    = colsumsq + HIDDIM;
  float* shift    = scale + HIDDIM;
  unsigned short* wpre_t = (unsigned short*)(shift + HIDDIM);  // 128 KB
  unsigned short* wop_t  = wpre_t + 65536;              // 128 KB
  int* deg      = (int*)(wop_t + 65536);                // 50000
  int* cursor   = deg + NNODES;                         // 50000
  int* rowptr   = cursor + NNODES;                      // 50001
  int* esrc     = rowptr + (NNODES + 1);                // 800000
  int* blocksum = esrc + NEDGES;                        // 256
  int* blockoff = blocksum + 256;                       // 256

  prep_k<<<512, 256, 0, stream>>>(W_pre, W_op, wpre_t, wop_t, colsum, colsumsq, deg);

  // CSR build
  hist_k<<<784, 256, 0, stream>>>(ei, deg);
  scanA_k<<<NB_SCAN, 256, 0, stream>>>(deg, rowptr, blocksum);
  scanB_k<<<1, 256, 0, stream>>>(blocksum, blockoff, rowptr);
  scanC_k<<<NB_SCAN, 256, 0, stream>>>(rowptr, blockoff, cursor);
  fill_k<<<1024, 256, 0, stream>>>(ei, cursor, esrc);

  // GEMM1 (fp32 A converted in staging) -> raw bf16 h + BN stats
  const int gx = (NNODES + 127) / 128;
  gemm_bf16_k<0><<<gx, 256, 0, stream>>>(s1, wpre_t, hbf, nullptr, colsum, colsumsq, NNODES);
  bn_finalize_k<<<1, HIDDIM, 0, stream>>>(colsum, colsumsq, gamma, betab, scale, shift);

  // gather + fused BN/ReLU + support mix
  agg_bn_support_k<<<(NNODES + 7) / 8, 256, 0, stream>>>(hbf, rowptr, esrc, x0,
                                                         scale, shift, supbf);

  // GEMM2 + GCNII epilogue
  gemm_bf16_k<1><<<gx, 256, 0, stream>>>(supbf, wop_t, out, supbf, nullptr, nullptr, NNODES);
}

// Round 10
// 230.257 us; speedup vs baseline: 1.1037x; 1.0023x over previous
//
#include <hip/hip_runtime.h>

#define NNODES 50000
#define NEDGES 800000
#define HIDDIM 256
#define NB_SCAN 196   // ceil(NNODES/256)

constexpr float kAlpha = 0.1f;
constexpr float kBnEps = 1e-5f;
constexpr float kBeta  = 0.40546510810816438198f;   // log(1.5)

typedef __attribute__((ext_vector_type(8))) short  bf16x8;   // 8 bf16 in 4 VGPRs
typedef __attribute__((ext_vector_type(4))) float  f32x4;

typedef __attribute__((address_space(1))) const unsigned int gu32;  // global
typedef __attribute__((address_space(3))) unsigned int       lu32;  // LDS

static __device__ __forceinline__ unsigned short f2bf(float f) {
  unsigned u = __float_as_uint(f);
  u = (u + 0x7FFFu + ((u >> 16) & 1u)) >> 16;      // RTNE
  return (unsigned short)u;
}
static __device__ __forceinline__ float bf2f(unsigned short h) {
  return __uint_as_float(((unsigned)h) << 16);
}

// ---------------------------------------------------------------------------
// prep: weight transposes (fp32 [k][n] -> bf16 [n][k]) + zero BN stats + deg
// ---------------------------------------------------------------------------
__global__ __launch_bounds__(256) void prep_k(const float* __restrict__ W_pre,
                                              const float* __restrict__ W_op,
                                              unsigned short* __restrict__ wpre_t,
                                              unsigned short* __restrict__ wop_t,
                                              float* __restrict__ colsum,
                                              float* __restrict__ colsumsq,
                                              int* __restrict__ deg) {
  int b = blockIdx.x, t = threadIdx.x;
  if (b < 256) {
    wpre_t[b * 256 + t] = f2bf(W_pre[t * 256 + b]);
    if (b == 0) { colsum[t] = 0.f; colsumsq[t] = 0.f; }
  } else {
    int n = b - 256;
    wop_t[n * 256 + t] = f2bf(W_op[t * 256 + n]);
  }
  if (b < NB_SCAN) {
    int idx = b * 256 + t;
    if (idx < NNODES) deg[idx] = 0;
  }
}

// ---------------------------------------------------------------------------
// bf16 MFMA GEMM: C = A[M,256] @ B[256,256], Bt transposed [n][k].
// 128x256 tile, BK=32, 8 K-steps, LDS double-buffer, ONE barrier per step:
// next step's global_load_lds issued before current step's ds_read+MFMA.
// XOR swizzle (row&3)<<4 on 64-B rows; source pre-swizzled for linear DMA.
// MODE 0: A fp32 (reg-staged + converted); C bf16 raw + column sum/sumsq
// MODE 1: A bf16 (global_load_lds); C fp32 = relu((1-beta)*S + beta*(A@B))
// ---------------------------------------------------------------------------
template<int MODE>
__global__ __launch_bounds__(256) void gemm_bf16_k(
    const void* __restrict__ Ain,
    const unsigned short* __restrict__ Bt,   // [256][256] bf16, Bt[n][k]
    void* __restrict__ Cout,                 // MODE0: bf16; MODE1: float
    const unsigned short* __restrict__ S,    // MODE1: residual bf16
    float* __restrict__ colsum,
    float* __restrict__ colsumsq,
    int M) {
  __shared__ unsigned short Al[2][128 * 32]; // 2 x 8 KB, row stride 64 B
  __shared__ unsigned short Bl[2][256 * 32]; // 2 x 16 KB
  __shared__ float cs[4][128], cq[4][128];   // MODE0 column-stat reduction

  const int t    = threadIdx.x;
  const int lane = t & 63;
  const int wid  = t >> 6;
  const int wr   = wid >> 1;                 // wave row (0/1): rows wr*64..+63
  const int wc   = wid & 1;                  // wave col (0/1): cols wc*128..+127
  const int row0 = blockIdx.x * 128;

  f32x4 acc[4][8] = {};

  // reg-staging assignment (MODE 0 A): thread -> (row, 16-k half)
  const int srow = t & 127;
  const int sseg = t >> 7;                   // 0: k0..15, 1: k16..31
  const int arow = row0 + srow;
  const bool aok = arow < M;
  const int swzA = (srow & 3) << 4;

  // global_load_lds lane decomposition: 1 issue = 1024 B = 16 rows x 64 B
  const int lrow = lane >> 2;                // row within 16-row group
  const int lchk = lane & 3;                 // 16B chunk within row
  const int lsw  = (lchk * 16) ^ ((lrow & 3) << 4);   // inverse-swizzled src off

  auto stage = [&](int b, int ks) {
    const int k0 = ks * 32;
    // ---- A ----
    if (MODE == 0) {
      const float* src = (const float*)Ain + (size_t)arow * 256 + k0 + sseg * 16;
      bf16x8 v0 = {}, v1 = {};
      if (aok) {
        float4 p0 = *(const float4*)(src + 0);
        float4 p1 = *(const float4*)(src + 4);
        float4 p2 = *(const float4*)(src + 8);
        float4 p3 = *(const float4*)(src + 12);
        v0[0] = (short)f2bf(p0.x); v0[1] = (short)f2bf(p0.y);
        v0[2] = (short)f2bf(p0.z); v0[3] = (short)f2bf(p0.w);
        v0[4] = (short)f2bf(p1.x); v0[5] = (short)f2bf(p1.y);
        v0[6] = (short)f2bf(p1.z); v0[7] = (short)f2bf(p1.w);
        v1[0] = (short)f2bf(p2.x); v1[1] = (short)f2bf(p2.y);
        v1[2] = (short)f2bf(p2.z); v1[3] = (short)f2bf(p2.w);
        v1[4] = (short)f2bf(p3.x); v1[5] = (short)f2bf(p3.y);
        v1[6] = (short)f2bf(p3.z); v1[7] = (short)f2bf(p3.w);
      }
      char* base = (char*)&Al[b][0] + srow * 64;
      *(bf16x8*)(base + ((sseg * 32 +  0) ^ swzA)) = v0;
      *(bf16x8*)(base + ((sseg * 32 + 16) ^ swzA)) = v1;
    } else {
#pragma unroll
      for (int c = 0; c < 2; ++c) {
        int chunk = wid * 2 + c;
        int row = chunk * 16 + lrow;         // 0..127 (OOB rows: garbage in ws, masked at store)
        const char* g = (const char*)Ain + ((size_t)(row0 + row) * 256 + k0) * 2 + lsw;
        char* l = (char*)&Al[b][0] + chunk * 1024 + lane * 16;
        __builtin_amdgcn_global_load_lds((gu32*)g, (lu32*)l, 16, 0, 0);
      }
    }
    // ---- B: 16 issues, 4 per wave ----
#pragma unroll
    for (int c = 0; c < 4; ++c) {
      int chunk = wid * 4 + c;
      int row = chunk * 16 + lrow;           // 0..255
      const char* g = (const char*)Bt + ((size_t)row * 256 + k0) * 2 + lsw;
      char* l = (char*)&Bl[b][0] + chunk * 1024 + lane * 16;
      __builtin_amdgcn_global_load_lds((gu32*)g, (lu32*)l, 16, 0, 0);
    }
  };

  stage(0, 0);
  __syncthreads();
  for (int ks = 0; ks < 8; ++ks) {
    const int cur = ks & 1;
    if (ks < 7) stage(cur ^ 1, ks + 1);      // loads fly under this step's MFMAs
    // ---- compute: 32 MFMA on buf[cur] ----
    const int koff = (lane >> 4) * 16;       // k-chunk byte offset
    bf16x8 af[4], bfr[8];
#pragma unroll
    for (int m = 0; m < 4; ++m) {
      int row = wr * 64 + m * 16 + (lane & 15);
      af[m] = *(const bf16x8*)((char*)&Al[cur][0] + row * 64 + (koff ^ ((row & 3) << 4)));
    }
#pragma unroll
    for (int n = 0; n < 8; ++n) {
      int nr = wc * 128 + n * 16 + (lane & 15);
      bfr[n] = *(const bf16x8*)((char*)&Bl[cur][0] + nr * 64 + (koff ^ ((nr & 3) << 4)));
    }
#pragma unroll
    for (int m = 0; m < 4; ++m)
#pragma unroll
      for (int n = 0; n < 8; ++n)
        acc[m][n] = __builtin_amdgcn_mfma_f32_16x16x32_bf16(af[m], bfr[n], acc[m][n], 0, 0, 0);
    __syncthreads();                         // drains loads into buf[cur^1]; protects buf[cur]
  }

  // ---- MODE 0: column sum / sumsq (OOB rows contributed exact zeros) ----
  if (MODE == 0) {
#pragma unroll
    for (int n = 0; n < 8; ++n) {
      float s = 0.f, q = 0.f;
#pragma unroll
      for (int m = 0; m < 4; ++m)
#pragma unroll
        for (int r = 0; r < 4; ++r) {
          float v = acc[m][n][r];
          s += v; q += v * v;
        }
      s += __shfl_xor(s, 16); s += __shfl_xor(s, 32);
      q += __shfl_xor(q, 16); q += __shfl_xor(q, 32);
      if (lane < 16) { cs[wid][n * 16 + lane] = s; cq[wid][n * 16 + lane] = q; }
    }
    __syncthreads();
    {
      int wcg = t >> 7;                      // column half (0/1)
      int lc  = t & 127;
      atomicAdd(&colsum[t],   cs[wcg][lc] + cs[wcg + 2][lc]);
      atomicAdd(&colsumsq[t], cq[wcg][lc] + cq[wcg + 2][lc]);
    }
  }

  // ---- store (C/D layout: col=lane&15, row=(lane>>4)*4+r) ----
#pragma unroll
  for (int m = 0; m < 4; ++m) {
    int rbase = row0 + wr * 64 + m * 16 + (lane >> 4) * 4;
#pragma unroll
    for (int r = 0; r < 4; ++r) {
      int row = rbase + r;
      if (row < M) {
#pragma unroll
        for (int n = 0; n < 8; ++n) {
          int col = wc * 128 + n * 16 + (lane & 15);
          float v = acc[m][n][r];
          if (MODE == 0) {
            ((unsigned short*)Cout)[(size_t)row * 256 + col] = f2bf(v);
          } else {
            float s = bf2f(S[(size_t)row * 256 + col]);
            ((float*)Cout)[(size_t)row * 256 + col] =
                fmaxf((1.f - kBeta) * s + kBeta * v, 0.f);
          }
        }
      }
    }
  }
}

// ---------------------------------------------------------------------------
// CSR build: degree histogram -> 3-phase parallel scan -> bucket src ids
// ---------------------------------------------------------------------------
__global__ __launch_bounds__(256) void hist_k(const int* __restrict__ ei,
                                              int* __restrict__ deg) {
  const int4* dst4 = (const int4*)(ei + NEDGES);
  const int n4 = NEDGES / 4;
  int stride = gridDim.x * blockDim.x;
  for (int i = blockIdx.x * blockDim.x + threadIdx.x; i < n4; i += stride) {
    int4 d = dst4[i];
    atomicAdd(&deg[d.x], 1);
    atomicAdd(&deg[d.y], 1);
    atomicAdd(&deg[d.z], 1);
    atomicAdd(&deg[d.w], 1);
  }
}

__global__ __launch_bounds__(256) void scanA_k(const int* __restrict__ deg,
                                               int* __restrict__ rowptr,
                                               int* __restrict__ blocksum) {
  __shared__ int sh[256];
  const int t = threadIdx.x;
  const int idx = blockIdx.x * 256 + t;
  int v = (idx < NNODES) ? deg[idx] : 0;
  sh[t] = v;
  __syncthreads();
  for (int off = 1; off < 256; off <<= 1) {
    int x = (t >= off) ? sh[t - off] : 0;
    __syncthreads();
    sh[t] += x;
    __syncthreads();
  }
  if (idx < NNODES) rowptr[idx] = sh[t] - v;      // exclusive within block
  if (t == 255) blocksum[blockIdx.x] = sh[255];
}

__global__ __launch_bounds__(256) void scanB_k(const int* __restrict__ blocksum,
                                               int* __restrict__ blockoff,
                                               int* __restrict__ rowptr) {
  __shared__ int sh[256];
  const int t = threadIdx.x;
  int v = (t < NB_SCAN) ? blocksum[t] : 0;
  sh[t] = v;
  __syncthreads();
  for (int off = 1; off < 256; off <<= 1) {
    int x = (t >= off) ? sh[t - off] : 0;
    __syncthreads();
    sh[t] += x;
    __syncthreads();
  }
  blockoff[t] = sh[t] - v;                        // exclusive block offset
  if (t == 255) rowptr[NNODES] = sh[255];         // grand total (=NEDGES)
}

// finalize rowptr and seed the fill cursor with absolute positions
__global__ __launch_bounds__(256) void scanC_k(int* __restrict__ rowptr,
                                               const int* __restrict__ blockoff,
                                               int* __restrict__ cursor) {
  const int idx = blockIdx.x * 256 + threadIdx.x;
  if (idx < NNODES) {
    int rp = rowptr[idx] + blockoff[blockIdx.x];
    rowptr[idx] = rp;
    cursor[idx] = rp;
  }
}

__global__ __launch_bounds__(256) void fill_k(const int* __restrict__ ei,
                                              int* __restrict__ cursor,
                                              int* __restrict__ esrc) {
  const int4* src4 = (const int4*)ei;
  const int4* dst4 = (const int4*)(ei + NEDGES);
  const int n4 = NEDGES / 4;
  int stride = gridDim.x * blockDim.x;
  for (int i = blockIdx.x * blockDim.x + threadIdx.x; i < n4; i += stride) {
    int4 s = src4[i];
    int4 d = dst4[i];
    esrc[atomicAdd(&cursor[d.x], 1)] = s.x;
    esrc[atomicAdd(&cursor[d.y], 1)] = s.y;
    esrc[atomicAdd(&cursor[d.z], 1)] = s.z;
    esrc[atomicAdd(&cursor[d.w], 1)] = s.w;
  }
}

// ---------------------------------------------------------------------------
// Gather-sum per destination node with FUSED BatchNorm-finalize + BN/ReLU +
// GCNII support mix. Half-wave (32 lanes x 16B) per node; neighbor indices
// pre-loaded cooperatively and broadcast via shfl (off the critical path);
// gathers unrolled x4. x0 loads / supp stores non-temporal.
// ---------------------------------------------------------------------------
__global__ __launch_bounds__(256) void agg_bn_support_k(
    const unsigned short* __restrict__ hb,   // [N][256] raw bf16
    const int* __restrict__ rowptr,
    const int* __restrict__ esrc,
    const float* __restrict__ x0,
    const float* __restrict__ colsum,
    const float* __restrict__ colsumsq,
    const float* __restrict__ gamma,
    const float* __restrict__ beta_bn,
    unsigned short* __restrict__ supp_bf) {
  __shared__ float s_sc[256], s_sh[256];
  {
    int j = threadIdx.x;
    float inv_n = 1.0f / (float)NNODES;
    float mu  = colsum[j] * inv_n;
    float var = colsumsq[j] * inv_n - mu * mu;
    float rstd = rsqrtf(var + kBnEps);
    float g = gamma[j] * rstd;
    s_sc[j] = g;
    s_sh[j] = beta_bn[j] - mu * g;
  }
  __syncthreads();

  const int hw   = threadIdx.x >> 5;         // half-wave in block (0..7)
  const int lane = threadIdx.x & 31;
  const int d    = blockIdx.x * 8 + hw;      // grid sized exactly: no guard needed
  const int off  = lane * 8;                 // 8 bf16 elems = 16 B per lane

  float sc[8], sh[8];
  *(float4*)&sc[0] = *(const float4*)(s_sc + off);
  *(float4*)&sc[4] = *(const float4*)(s_sc + off + 4);
  *(float4*)&sh[0] = *(const float4*)(s_sh + off);
  *(float4*)&sh[4] = *(const float4*)(s_sh + off + 4);

  const int beg = rowptr[d];
  const int end = rowptr[d + 1];
  float acc[8] = {0.f, 0.f, 0.f, 0.f, 0.f, 0.f, 0.f, 0.f};

  for (int bb = beg; bb < end; bb += 32) {
    int cnt = end - bb; if (cnt > 32) cnt = 32;
    int myi = esrc[bb + ((lane < cnt) ? lane : 0)];   // cooperative index load
    int u = 0;
    for (; u + 3 < cnt; u += 4) {
      int s0 = __shfl(myi, u, 32),     s1 = __shfl(myi, u + 1, 32);
      int s2 = __shfl(myi, u + 2, 32), s3 = __shfl(myi, u + 3, 32);
      bf16x8 v0 = *(const bf16x8*)(hb + (size_t)s0 * HIDDIM + off);
      bf16x8 v1 = *(const bf16x8*)(hb + (size_t)s1 * HIDDIM + off);
      bf16x8 v2 = *(const bf16x8*)(hb + (size_t)s2 * HIDDIM + off);
      bf16x8 v3 = *(const bf16x8*)(hb + (size_t)s3 * HIDDIM + off);
#pragma unroll
      for (int j = 0; j < 8; ++j) {
        acc[j] += fmaxf(fmaf(bf2f((unsigned short)v0[j]), sc[j], sh[j]), 0.f)
                + fmaxf(fmaf(bf2f((unsigned short)v1[j]), sc[j], sh[j]), 0.f)
                + fmaxf(fmaf(bf2f((unsigned short)v2[j]), sc[j], sh[j]), 0.f)
                + fmaxf(fmaf(bf2f((unsigned short)v3[j]), sc[j], sh[j]), 0.f);
      }
    }
    for (; u < cnt; ++u) {
      int s0 = __shfl(myi, u, 32);
      bf16x8 v0 = *(const bf16x8*)(hb + (size_t)s0 * HIDDIM + off);
#pragma unroll
      for (int j = 0; j < 8; ++j)
        acc[j] += fmaxf(fmaf(bf2f((unsigned short)v0[j]), sc[j], sh[j]), 0.f);
    }
  }

  // self term + initial residual (x0 non-temporal: no reuse)
  bf16x8 vd = *(const bf16x8*)(hb + (size_t)d * HIDDIM + off);
  f32x4 xa = __builtin_nontemporal_load((const f32x4*)(x0 + (size_t)d * HIDDIM + off));
  f32x4 xb = __builtin_nontemporal_load((const f32x4*)(x0 + (size_t)d * HIDDIM + off + 4));
  float xs[8] = {xa.x, xa.y, xa.z, xa.w, xb.x, xb.y, xb.z, xb.w};
  bf16x8 o;
#pragma unroll
  for (int j = 0; j < 8; ++j) {
    float hv = fmaxf(fmaf(bf2f((unsigned short)vd[j]), sc[j], sh[j]), 0.f);
    o[j] = (short)f2bf((1.f - kAlpha) * (hv + acc[j]) + kAlpha * xs[j]);
  }
  __builtin_nontemporal_store(o, (bf16x8*)(supp_bf + (size_t)d * HIDDIM + off));
}

// ---------------------------------------------------------------------------
extern "C" void kernel_launch(void* const* d_in, const int* in_sizes, int n_in,
                              void* d_out, int out_size, void* d_ws, size_t ws_size,
                              hipStream_t stream) {
  // inputs: s0, s1, x_0, W_pre, gamma, beta_bn, W_op, edge_index, drop_prob, training
  const float* s1    = (const float*)d_in[1];
  const float* x0    = (const float*)d_in[2];
  const float* W_pre = (const float*)d_in[3];
  const float* gamma = (const float*)d_in[4];
  const float* betab = (const float*)d_in[5];
  const float* W_op  = (const float*)d_in[6];
  const int*   ei    = (const int*)d_in[7];
  float* out = (float*)d_out;

  const size_t NH = (size_t)NNODES * HIDDIM;            // 12.8M elements
  unsigned short* hbf   = (unsigned short*)d_ws;        // 25.6 MB (raw bf16 h)
  unsigned short* supbf = hbf + NH;                     // 25.6 MB
  float* colsum   = (float*)(supbf + NH);               // 256
  float* colsumsq = colsum + HIDDIM;
  unsigned short* wpre_t = (unsigned short*)(colsumsq + HIDDIM);  // 128 KB
  unsigned short* wop_t  = wpre_t + 65536;              // 128 KB
  int* deg      = (int*)(wop_t + 65536);                // 50000
  int* cursor   = deg + NNODES;                         // 50000
  int* rowptr   = cursor + NNODES;                      // 50001
  int* esrc     = rowptr + (NNODES + 1);                // 800000
  int* blocksum = esrc + NEDGES;                        // 256
  int* blockoff = blocksum + 256;                       // 256

  prep_k<<<512, 256, 0, stream>>>(W_pre, W_op, wpre_t, wop_t, colsum, colsumsq, deg);

  // CSR build
  hist_k<<<784, 256, 0, stream>>>(ei, deg);
  scanA_k<<<NB_SCAN, 256, 0, stream>>>(deg, rowptr, blocksum);
  scanB_k<<<1, 256, 0, stream>>>(blocksum, blockoff, rowptr);
  scanC_k<<<NB_SCAN, 256, 0, stream>>>(rowptr, blockoff, cursor);
  fill_k<<<1024, 256, 0, stream>>>(ei, cursor, esrc);

  // GEMM1 (fp32 A converted in staging) -> raw bf16 h + BN stats
  const int gx = (NNODES + 127) / 128;
  gemm_bf16_k<0><<<gx, 256, 0, stream>>>(s1, wpre_t, hbf, nullptr, colsum, colsumsq, NNODES);

  // gather + fused BN-finalize/BN/ReLU + support mix
  agg_bn_support_k<<<(NNODES + 7) / 8, 256, 0, stream>>>(hbf, rowptr, esrc, x0,
                                                         colsum, colsumsq, gamma, betab,
                                                         supbf);

  // GEMM2 + GCNII epilogue
  gemm_bf16_k<1><<<gx, 256, 0, stream>>>(supbf, wop_t, out, supbf, nullptr, nullptr, NNODES);
}